// Round 30
// baseline (275.428 us; speedup 1.0000x reference)
//
#include <hip/hip_runtime.h>
#include <math.h>

typedef _Float16 h16;
typedef _Float16 f16x8 __attribute__((ext_vector_type(8)));
typedef _Float16 f16x4 __attribute__((ext_vector_type(4)));
typedef float f32x4 __attribute__((ext_vector_type(4)));

enum { EPI_F32 = 0, EPI_SPLIT2 = 1, EPI_VT = 2, EPI_H16 = 3 };
enum { M_SINGLE = 0, M_DBUF = 1 };

struct GP {
  const h16* Ah; const h16* Al;
  const h16* Bh; const h16* Bl;
  const float* bias;
  float* outF;
  h16* oQh; h16* oQl; h16* oKh; h16* oKl;
  h16* outH;
  int K, lda, ldb, ldc;
  size_t sA, sB, sO;          // per-batch (blockIdx.z) element strides
};

__device__ __forceinline__ f32x4 mfma16(f16x8 a, f16x8 b, f32x4 c) {
  return __builtin_amdgcn_mfma_f32_16x16x32_f16(a, b, c, 0, 0, 0);
}

// async global->LDS, 16B per lane; LDS dest = wave-uniform base + lane*16
__device__ __forceinline__ void glds16(const h16* g, h16* l) {
  __builtin_amdgcn_global_load_lds((const __attribute__((address_space(1))) void*)g,
                                   (__attribute__((address_space(3))) void*)l,
                                   16, 0, 0);
}

// C[M,N] = A[M,K] @ B[N,K]^T (both K-contiguous fp16), fp32 accum.
// TERMS: 1 = AhBh; 2 = +AlBh; 3 = +AhBl.  BSPL: B has lo part.
// BK=64; T2 swizzle, linear LDS dest (rule #21): src col (lane&7)^(lane>>3),
// read (ks*4+fq)^(fr&7) -> 0 bank conflicts (measured r10).
// FINAL CONFIG (r28/r29, measured 271.5/272.4us; design space closed r15-r26):
//   QK: 512t M_SINGLE (96us, MfmaUtil 51%; beats 256t/BN64/dbuf128K/M_PIPE/dbufBK32)
//   V-proj, PV: 512t M_DBUF 48KB (long/medium-K)
//   scores, outproj: 256t (short-K regresses at 512t r17/r19 and dbufBK32 r26)
//   prep_all: full fusion incl. split_x (r28: -7us vs split launches)
// XCD-chunked swizzle (T1) needs nwg%8==0.
template<int BLK, int BM, int BN, int BSPL, int TERMS, int EPI, bool CSKIP, bool KLIM, int MODE>
__global__ __launch_bounds__(BLK, (BLK == 512 ? 4 : 2)) void gemm_bt(GP p)
{
  constexpr int BK = 64;
  constexpr bool ASPL = (TERMS >= 2);
  constexpr int NW = BLK / 64;                // waves per block
  constexpr int WR = 2, WC = NW / 2;          // wave grid rows x cols
  constexpr int WM = BM / WR, WN = BN / WC;   // per-wave output tile
  constexpr int FM = WM / 16, FN = WN / 16;
  constexpr int AH = BM * BK, BH = BN * BK;   // per-half LDS elements

  const int gx = gridDim.x, gy = gridDim.y;
  int lin = blockIdx.x + gx * blockIdx.y;
  const int nwg = gx * gy;
  if ((nwg & 7) == 0) lin = (lin & 7) * (nwg >> 3) + (lin >> 3);
  const int m0 = (lin / gx) * BM;
  const int n0 = (lin % gx) * BN;
  if (CSKIP && n0 >= m0 + BM) return;         // tile fully above causal diagonal
  const int z = blockIdx.z;
  const h16* Ah = p.Ah + (size_t)z * p.sA;
  const h16* Al = ASPL ? p.Al + (size_t)z * p.sA : (const h16*)nullptr;
  const h16* Bh = p.Bh + (size_t)z * p.sB;
  const h16* Bl = BSPL ? p.Bl + (size_t)z * p.sB : (const h16*)nullptr;

  constexpr int NBUF = (MODE == M_SINGLE) ? 1 : 2;
  __shared__ h16 sAh[NBUF * AH];
  __shared__ h16 sAl[ASPL ? NBUF * AH : 8];
  __shared__ h16 sBh[NBUF * BH];
  __shared__ h16 sBl[BSPL ? NBUF * BH : 8];

  const int tid = threadIdx.x;
  const int lane = tid & 63;
  const int w = tid >> 6;
  const int wm = (w / WC) * WM;
  const int wn = (w % WC) * WN;
  const int fr = lane & 15;
  const int fq = lane >> 4;
  const int lrow = lane >> 3;                        // 0..7: row within 8-row chunk
  const int lcol = (((lane & 7) ^ lrow) * 8);        // swizzled global col (h16 units)

  f32x4 acc[FM][FN];
#pragma unroll
  for (int i = 0; i < FM; i++)
#pragma unroll
    for (int j = 0; j < FN; j++) acc[i][j] = f32x4{0.f, 0.f, 0.f, 0.f};

  const int kend = KLIM ? ((m0 + BM < p.K) ? (m0 + BM) : p.K) : p.K;

  auto stage = [&](int k0, int half) {
    const int ao = half * AH, bo = half * BH;
#pragma unroll
    for (int i = w; i < BM / 8; i += NW)
      glds16(Ah + (size_t)(m0 + i * 8 + lrow) * p.lda + (k0 + lcol), &sAh[ao + i * 512]);
    if constexpr (ASPL) {
#pragma unroll
      for (int i = w; i < BM / 8; i += NW)
        glds16(Al + (size_t)(m0 + i * 8 + lrow) * p.lda + (k0 + lcol), &sAl[ao + i * 512]);
    }
#pragma unroll
    for (int i = w; i < BN / 8; i += NW)
      glds16(Bh + (size_t)(n0 + i * 8 + lrow) * p.ldb + (k0 + lcol), &sBh[bo + i * 512]);
    if constexpr (BSPL) {
#pragma unroll
      for (int i = w; i < BN / 8; i += NW)
        glds16(Bl + (size_t)(n0 + i * 8 + lrow) * p.ldb + (k0 + lcol), &sBl[bo + i * 512]);
    }
  };

  auto compute = [&](int half) {
    const int ca = half * AH, cb = half * BH;
#pragma unroll
    for (int ks = 0; ks < 2; ks++) {
      const int swo = (((ks * 4 + fq) ^ (fr & 7)) * 8);   // un-swizzled read offset
      f16x8 fa[FM], fb[FN];
      f16x8 fal[ASPL ? FM : 1], fbl[BSPL ? FN : 1];
#pragma unroll
      for (int m = 0; m < FM; m++) {
        fa[m] = *(const f16x8*)&sAh[ca + (wm + m * 16 + fr) * BK + swo];
        if constexpr (ASPL)
          fal[m] = *(const f16x8*)&sAl[ca + (wm + m * 16 + fr) * BK + swo];
      }
#pragma unroll
      for (int n = 0; n < FN; n++) {
        fb[n] = *(const f16x8*)&sBh[cb + (wn + n * 16 + fr) * BK + swo];
        if constexpr (BSPL)
          fbl[n] = *(const f16x8*)&sBl[cb + (wn + n * 16 + fr) * BK + swo];
      }
#pragma unroll
      for (int m = 0; m < FM; m++)
#pragma unroll
        for (int n = 0; n < FN; n++) {
          acc[m][n] = mfma16(fa[m], fb[n], acc[m][n]);
          if constexpr (TERMS >= 2) acc[m][n] = mfma16(fal[m], fb[n], acc[m][n]);
          if constexpr (TERMS >= 3) acc[m][n] = mfma16(fa[m], fbl[n], acc[m][n]);
        }
    }
  };

  if constexpr (MODE == M_DBUF) {
    const int nIter = kend / BK;
    stage(0, 0);
    for (int it = 0; it < nIter; ++it) {
      __syncthreads();
      if (it + 1 < nIter) stage((it + 1) * BK, (it + 1) & 1);
      compute(it & 1);
    }
  } else {
    for (int k0 = 0; k0 < kend; k0 += BK) {
      __syncthreads();
      stage(k0, 0);
      __syncthreads();
      compute(0);
    }
  }

  // ---- epilogue ----  C/D layout: col = lane&15, row = (lane>>4)*4 + reg
#pragma unroll
  for (int m = 0; m < FM; m++) {
    const int grb = m0 + wm + m * 16 + fq * 4;
#pragma unroll
    for (int n = 0; n < FN; n++) {
      const int gc = n0 + wn + n * 16 + fr;
      if constexpr (EPI == EPI_F32) {
        float* o = p.outF + (size_t)z * p.sO;
#pragma unroll
        for (int r = 0; r < 4; r++)
          o[(size_t)(grb + r) * p.ldc + gc] = acc[m][n][r];
      } else if constexpr (EPI == EPI_SPLIT2) {
        const float bv = p.bias[gc];
#pragma unroll
        for (int r = 0; r < 4; r++) {
          const float v = acc[m][n][r] + bv;
          const h16 h = (h16)v;
          const h16 l = (h16)(v - (float)h);
          const size_t idx = (size_t)(grb + r) * 512;
          if (gc < 512) { p.oQh[idx + gc] = h; p.oQl[idx + gc] = l; }
          else          { p.oKh[idx + gc - 512] = h; p.oKl[idx + gc - 512] = l; }
        }
      } else if constexpr (EPI == EPI_VT) {
        const float bv = p.bias[gc];
        f16x4 pk;
#pragma unroll
        for (int r = 0; r < 4; r++) pk[r] = (h16)(acc[m][n][r] + bv);
        const int bb = grb >> 11;               // batch
        const int t  = grb & 2047;              // token (multiple of 4)
        *(f16x4*)(p.outH + ((size_t)bb * 512 + gc) * 2048 + t) = pk;
      } else { // EPI_H16
        h16* o = p.outH + (size_t)z * p.sO;
#pragma unroll
        for (int r = 0; r < 4; r++)
          o[(size_t)(grb + r) * p.ldc + gc] = (h16)acc[m][n][r];
      }
    }
  }
}

// Fused prep: split_x (8192 blocks) + prep_wqk (8192) + prep_wv (4096) +
// prep_projT (1024) = 21504 blocks, one launch. All independent, memory-bound.
__global__ __launch_bounds__(256) void prep_all(
    const float* __restrict__ x, h16* __restrict__ xh, h16* __restrict__ xl,
    const float* __restrict__ WQ, const float* __restrict__ bQ,
    const float* __restrict__ WK, const float* __restrict__ bK,
    h16* __restrict__ Wh, h16* __restrict__ Wl, float* __restrict__ bias_qk,
    const float* __restrict__ WV, const float* __restrict__ bV,
    h16* __restrict__ Wv, float* __restrict__ bias_v,
    const float* __restrict__ proj, h16* __restrict__ projT)
{
  const int b = blockIdx.x;
  if (b < 8192) {                       // ---- split_x ----
    const size_t i = ((size_t)b * 256 + threadIdx.x) * 8;
    const float4 a = *(const float4*)(x + i);
    const float4 c = *(const float4*)(x + i + 4);
    const float vv[8] = {a.x, a.y, a.z, a.w, c.x, c.y, c.z, c.w};
    f16x8 h, l;
#pragma unroll
    for (int j = 0; j < 8; j++) {
      const h16 hh = (h16)vv[j];
      h[j] = hh;
      l[j] = (h16)(vv[j] - (float)hh);
    }
    *(f16x8*)(xh + i) = h;
    *(f16x8*)(xl + i) = l;
  } else if (b < 16384) {               // ---- prep_wqk ----
    const int idx = (b - 8192) * 256 + threadIdx.x;
    const int n = idx >> 11;
    const int k = idx & 2047;
    float v;
    if (n < 512) {
      const int g = n >> 7, e = n & 127;
      const size_t base = (size_t)(128 * g + e) * 2048 + k;   // head 4j+g rows
      v = WQ[base] + WQ[base + (size_t)512 * 2048] + WQ[base + (size_t)1024 * 2048]
        + WQ[base + (size_t)1536 * 2048];
    } else {
      v = WK[(size_t)(n - 512) * 2048 + k];
    }
    const h16 h = (h16)v;
    Wh[idx] = h;
    Wl[idx] = (h16)(v - (float)h);
    if (k == 0) {
      if (n < 512) {
        const int g = n >> 7, e = n & 127;
        const int r = 128 * g + e;
        bias_qk[n] = bQ[r] + bQ[r + 512] + bQ[r + 1024] + bQ[r + 1536];
      } else {
        bias_qk[n] = bK[n - 512];
      }
    }
  } else if (b < 20480) {               // ---- prep_wv ----
    const int idx = (b - 16384) * 256 + threadIdx.x;
    Wv[idx] = (h16)WV[idx];
    if ((idx & 2047) == 0) bias_v[idx >> 11] = bV[idx >> 11];
  } else {                              // ---- prep_projT ----
    const int idx = (b - 20480) * 256 + threadIdx.x;
    const int n = idx >> 9;
    const int o = (idx & 511) << 2;
    const int g = n >> 7, e = n & 127;
    const size_t base = (size_t)(128 * g + e) * 2048 + o;
    const float4 a = *(const float4*)(proj + base);
    const float4 c = *(const float4*)(proj + base + (size_t)512 * 2048);
    const float4 d = *(const float4*)(proj + base + (size_t)1024 * 2048);
    const float4 f = *(const float4*)(proj + base + (size_t)1536 * 2048);
    projT[(size_t)(o + 0) * 512 + n] = (h16)(a.x + c.x + d.x + f.x);
    projT[(size_t)(o + 1) * 512 + n] = (h16)(a.y + c.y + d.y + f.y);
    projT[(size_t)(o + 2) * 512 + n] = (h16)(a.z + c.z + d.z + f.z);
    projT[(size_t)(o + 3) * 512 + n] = (h16)(a.w + c.w + d.w + f.w);
  }
}

// Batched causal row softmax; blockIdx.x = b*2048 + t. attn = softmax/sqrt(128).
__global__ __launch_bounds__(256) void softmax_row(const float* __restrict__ sc,
                                                   h16* __restrict__ attn)
{
  const int bt = blockIdx.x;
  const int t = bt & 2047;
  const int tid = threadIdx.x;
  const int lane = tid & 63;
  const int wid = tid >> 6;
  const int len = t + 1;
  const size_t rowoff = (size_t)bt * 2048;
  const float* row = sc + rowoff;
  const int c0 = tid * 8;
  float v[8];
  if (c0 < len) {
    const float4 a = *(const float4*)(row + c0);
    const float4 b = *(const float4*)(row + c0 + 4);
    v[0] = a.x; v[1] = a.y; v[2] = a.z; v[3] = a.w;
    v[4] = b.x; v[5] = b.y; v[6] = b.z; v[7] = b.w;
#pragma unroll
    for (int j = 0; j < 8; j++)
      if (c0 + j >= len) v[j] = -INFINITY;
  } else {
#pragma unroll
    for (int j = 0; j < 8; j++) v[j] = -INFINITY;
  }
  float m = v[0];
#pragma unroll
  for (int j = 1; j < 8; j++) m = fmaxf(m, v[j]);
#pragma unroll
  for (int off = 32; off > 0; off >>= 1) m = fmaxf(m, __shfl_xor(m, off));
  __shared__ float redm[4];
  if (lane == 0) redm[wid] = m;
  __syncthreads();
  m = fmaxf(fmaxf(redm[0], redm[1]), fmaxf(redm[2], redm[3]));
  float e[8];
  float s = 0.f;
#pragma unroll
  for (int j = 0; j < 8; j++) { e[j] = expf(v[j] - m); s += e[j]; }
#pragma unroll
  for (int off = 32; off > 0; off >>= 1) s += __shfl_xor(s, off);
  __shared__ float reds[4];
  if (lane == 0) reds[wid] = s;
  __syncthreads();
  s = reds[0] + reds[1] + reds[2] + reds[3];
  const float inv = 1.f / (s * 11.313708498984761f);   // * sqrt(128)
  const int tend = ((t >> 7) + 1) << 7;                // row's causal tile end
  if (c0 < tend) {
    f16x8 o;
#pragma unroll
    for (int j = 0; j < 8; j++) o[j] = (h16)(e[j] * inv);
    *(f16x8*)(attn + rowoff + c0) = o;
  }
}

extern "C" void kernel_launch(void* const* d_in, const int* in_sizes, int n_in,
                              void* d_out, int out_size, void* d_ws, size_t ws_size,
                              hipStream_t stream)
{
  (void)in_sizes; (void)n_in;
  const float* x    = (const float*)d_in[0];
  const float* WQ   = (const float*)d_in[1];
  const float* bQv  = (const float*)d_in[2];
  const float* WK   = (const float*)d_in[3];
  const float* bKv  = (const float*)d_in[4];
  const float* WV   = (const float*)d_in[5];
  const float* bVv  = (const float*)d_in[6];
  const float* proj = (const float*)d_in[7];
  float* out = (float*)d_out;

  char* ws = (char*)d_ws;
  size_t off = 0;
  auto alloc = [&](size_t bytes) -> void* {
    off = (off + 255) & ~(size_t)255;
    void* p = ws + off;
    off += bytes;
    return p;
  };
  // x split region (64MiB = xh+xl); 4-batch scores (64MiB fp32) aliases it after projections.
  char* xregion = (char*)alloc((size_t)2 * 16777216 * 2);
  h16* xh = (h16*)xregion;
  h16* xl = (h16*)(xregion + (size_t)16777216 * 2);
  float* scores = (float*)xregion;                       // [4][2048][2048] fp32
  h16* attn = (h16*)alloc((size_t)4 * 2048 * 2048 * 2);  // [4][2048][2048] fp16

  h16* Wqk_h = (h16*)alloc((size_t)1024 * 2048 * 2);
  h16* Wqk_l = (h16*)alloc((size_t)1024 * 2048 * 2);
  h16* Wv    = (h16*)alloc((size_t)512 * 2048 * 2);
  h16* projT = (h16*)alloc((size_t)2048 * 512 * 2);
  float* bias_qk = (float*)alloc(1024 * 4);
  float* bias_v  = (float*)alloc(512 * 4);
  h16* Qh = (h16*)alloc((size_t)8192 * 512 * 2);
  h16* Ql = (h16*)alloc((size_t)8192 * 512 * 2);
  h16* Kh = (h16*)alloc((size_t)8192 * 512 * 2);
  h16* Kl = (h16*)alloc((size_t)8192 * 512 * 2);
  h16* Vt = (h16*)alloc((size_t)4 * 512 * 2048 * 2);   // [b][d][t]
  h16* Zg = (h16*)alloc((size_t)8192 * 512 * 2);
  if (off > ws_size) {           // distinctive failure signal if ws too small
    hipMemsetAsync(d_out, 0x7F, (size_t)out_size * 4, stream);
    return;
  }

  prep_all<<<21504, 256, 0, stream>>>(x, xh, xl, WQ, bQv, WK, bKv, Wqk_h, Wqk_l,
                                      bias_qk, WV, bVv, Wv, bias_v, proj, projT);

  { // Qagg+K projection: 512t M_SINGLE (96us, MfmaUtil 51%)
    GP p{};
    p.Ah = xh; p.Al = xl; p.Bh = Wqk_h; p.Bl = Wqk_l; p.bias = bias_qk;
    p.oQh = Qh; p.oQl = Ql; p.oKh = Kh; p.oKl = Kl;
    p.K = 2048; p.lda = 2048; p.ldb = 2048; p.ldc = 0;
    gemm_bt<512, 128, 128, 1, 3, EPI_SPLIT2, false, false, M_SINGLE><<<dim3(8, 64, 1), 512, 0, stream>>>(p);
  }
  { // V projection (hi-only) -> Vt; 512t dbuf 48KB
    GP p{};
    p.Ah = xh; p.Bh = Wv; p.bias = bias_v; p.outH = Vt;
    p.K = 2048; p.lda = 2048; p.ldb = 2048; p.ldc = 0;
    gemm_bt<512, 128, 64, 0, 1, EPI_VT, false, false, M_DBUF><<<dim3(8, 64, 1), 512, 0, stream>>>(p);
  }
  // xh/xl dead from here; scores alias their storage.
  { // scores = Qagg @ K^T: 256t single-buffer, causal tile skip
    GP p{};
    p.Ah = Qh; p.Al = Ql; p.Bh = Kh; p.Bl = Kl; p.outF = scores;
    p.K = 512; p.lda = 512; p.ldb = 512; p.ldc = 2048;
    p.sA = (size_t)2048 * 512; p.sB = (size_t)2048 * 512; p.sO = (size_t)2048 * 2048;
    gemm_bt<256, 128, 128, 1, 3, EPI_F32, true, false, M_SINGLE><<<dim3(16, 16, 4), 256, 0, stream>>>(p);
  }
  softmax_row<<<8192, 256, 0, stream>>>(scores, attn);
  { // Zg = attn @ Vt^T: 512t dbuf 48KB klim
    GP p{};
    p.Ah = attn; p.Bh = Vt; p.outH = Zg;
    p.K = 2048; p.lda = 2048; p.ldb = 2048; p.ldc = 512;
    p.sA = (size_t)2048 * 2048; p.sB = (size_t)512 * 2048; p.sO = (size_t)2048 * 512;
    gemm_bt<512, 128, 64, 0, 1, EPI_H16, false, true, M_DBUF><<<dim3(8, 16, 4), 512, 0, stream>>>(p);
  }
  { // out = Zg @ projAgg: 256t dbuf 64KB
    GP p{};
    p.Ah = Zg; p.Bh = projT; p.outF = out;
    p.K = 512; p.lda = 512; p.ldb = 512; p.ldc = 2048;
    gemm_bt<256, 128, 128, 0, 1, EPI_F32, false, false, M_DBUF><<<dim3(16, 64, 1), 256, 0, stream>>>(p);
  }
}

// Round 31
// 272.211 us; speedup vs baseline: 1.0118x; 1.0118x over previous
//
#include <hip/hip_runtime.h>
#include <math.h>

typedef _Float16 h16;
typedef _Float16 f16x8 __attribute__((ext_vector_type(8)));
typedef _Float16 f16x4 __attribute__((ext_vector_type(4)));
typedef float f32x4 __attribute__((ext_vector_type(4)));

enum { EPI_F32 = 0, EPI_SPLIT2 = 1, EPI_VT = 2, EPI_H16 = 3 };
enum { M_SINGLE = 0, M_DBUF = 1 };

struct GP {
  const h16* Ah; const h16* Al;
  const h16* Bh; const h16* Bl;
  const float* bias;
  float* outF;
  h16* oQh; h16* oQl; h16* oKh; h16* oKl;
  h16* outH;
  int K, lda, ldb, ldc;
  size_t sA, sB, sO;          // per-batch (blockIdx.z) element strides
};

__device__ __forceinline__ f32x4 mfma16(f16x8 a, f16x8 b, f32x4 c) {
  return __builtin_amdgcn_mfma_f32_16x16x32_f16(a, b, c, 0, 0, 0);
}

// async global->LDS, 16B per lane; LDS dest = wave-uniform base + lane*16
__device__ __forceinline__ void glds16(const h16* g, h16* l) {
  __builtin_amdgcn_global_load_lds((const __attribute__((address_space(1))) void*)g,
                                   (__attribute__((address_space(3))) void*)l,
                                   16, 0, 0);
}

// C[M,N] = A[M,K] @ B[N,K]^T (both K-contiguous fp16), fp32 accum.
// TERMS: 1 = AhBh; 2 = +AlBh; 3 = +AhBl.  BSPL: B has lo part.
// BK=64; T2 swizzle, linear LDS dest (rule #21): src col (lane&7)^(lane>>3),
// read (ks*4+fq)^(fr&7) -> 0 bank conflicts (measured r10).
// FINAL CONFIG (r28-r30, measured 271.5/272.4/275.4us; space closed r15-r26):
//   QK: 512t M_SINGLE (96us, MfmaUtil 51%; beats 256t/BN64/dbuf128K/M_PIPE/dbufBK32)
//   V-proj, PV: 512t M_DBUF 48KB (long/medium-K)
//   scores, outproj: 256t (short-K regresses at 512t r17/r19 and dbufBK32 r26)
//   prep_all: full fusion incl. split_x (r28: -7us vs split launches)
// XCD-chunked swizzle (T1) needs nwg%8==0.
template<int BLK, int BM, int BN, int BSPL, int TERMS, int EPI, bool CSKIP, bool KLIM, int MODE>
__global__ __launch_bounds__(BLK, (BLK == 512 ? 4 : 2)) void gemm_bt(GP p)
{
  constexpr int BK = 64;
  constexpr bool ASPL = (TERMS >= 2);
  constexpr int NW = BLK / 64;                // waves per block
  constexpr int WR = 2, WC = NW / 2;          // wave grid rows x cols
  constexpr int WM = BM / WR, WN = BN / WC;   // per-wave output tile
  constexpr int FM = WM / 16, FN = WN / 16;
  constexpr int AH = BM * BK, BH = BN * BK;   // per-half LDS elements

  const int gx = gridDim.x, gy = gridDim.y;
  int lin = blockIdx.x + gx * blockIdx.y;
  const int nwg = gx * gy;
  if ((nwg & 7) == 0) lin = (lin & 7) * (nwg >> 3) + (lin >> 3);
  const int m0 = (lin / gx) * BM;
  const int n0 = (lin % gx) * BN;
  if (CSKIP && n0 >= m0 + BM) return;         // tile fully above causal diagonal
  const int z = blockIdx.z;
  const h16* Ah = p.Ah + (size_t)z * p.sA;
  const h16* Al = ASPL ? p.Al + (size_t)z * p.sA : (const h16*)nullptr;
  const h16* Bh = p.Bh + (size_t)z * p.sB;
  const h16* Bl = BSPL ? p.Bl + (size_t)z * p.sB : (const h16*)nullptr;

  constexpr int NBUF = (MODE == M_SINGLE) ? 1 : 2;
  __shared__ h16 sAh[NBUF * AH];
  __shared__ h16 sAl[ASPL ? NBUF * AH : 8];
  __shared__ h16 sBh[NBUF * BH];
  __shared__ h16 sBl[BSPL ? NBUF * BH : 8];

  const int tid = threadIdx.x;
  const int lane = tid & 63;
  const int w = tid >> 6;
  const int wm = (w / WC) * WM;
  const int wn = (w % WC) * WN;
  const int fr = lane & 15;
  const int fq = lane >> 4;
  const int lrow = lane >> 3;                        // 0..7: row within 8-row chunk
  const int lcol = (((lane & 7) ^ lrow) * 8);        // swizzled global col (h16 units)

  f32x4 acc[FM][FN];
#pragma unroll
  for (int i = 0; i < FM; i++)
#pragma unroll
    for (int j = 0; j < FN; j++) acc[i][j] = f32x4{0.f, 0.f, 0.f, 0.f};

  const int kend = KLIM ? ((m0 + BM < p.K) ? (m0 + BM) : p.K) : p.K;

  auto stage = [&](int k0, int half) {
    const int ao = half * AH, bo = half * BH;
#pragma unroll
    for (int i = w; i < BM / 8; i += NW)
      glds16(Ah + (size_t)(m0 + i * 8 + lrow) * p.lda + (k0 + lcol), &sAh[ao + i * 512]);
    if constexpr (ASPL) {
#pragma unroll
      for (int i = w; i < BM / 8; i += NW)
        glds16(Al + (size_t)(m0 + i * 8 + lrow) * p.lda + (k0 + lcol), &sAl[ao + i * 512]);
    }
#pragma unroll
    for (int i = w; i < BN / 8; i += NW)
      glds16(Bh + (size_t)(n0 + i * 8 + lrow) * p.ldb + (k0 + lcol), &sBh[bo + i * 512]);
    if constexpr (BSPL) {
#pragma unroll
      for (int i = w; i < BN / 8; i += NW)
        glds16(Bl + (size_t)(n0 + i * 8 + lrow) * p.ldb + (k0 + lcol), &sBl[bo + i * 512]);
    }
  };

  auto compute = [&](int half) {
    const int ca = half * AH, cb = half * BH;
#pragma unroll
    for (int ks = 0; ks < 2; ks++) {
      const int swo = (((ks * 4 + fq) ^ (fr & 7)) * 8);   // un-swizzled read offset
      f16x8 fa[FM], fb[FN];
      f16x8 fal[ASPL ? FM : 1], fbl[BSPL ? FN : 1];
#pragma unroll
      for (int m = 0; m < FM; m++) {
        fa[m] = *(const f16x8*)&sAh[ca + (wm + m * 16 + fr) * BK + swo];
        if constexpr (ASPL)
          fal[m] = *(const f16x8*)&sAl[ca + (wm + m * 16 + fr) * BK + swo];
      }
#pragma unroll
      for (int n = 0; n < FN; n++) {
        fb[n] = *(const f16x8*)&sBh[cb + (wn + n * 16 + fr) * BK + swo];
        if constexpr (BSPL)
          fbl[n] = *(const f16x8*)&sBl[cb + (wn + n * 16 + fr) * BK + swo];
      }
#pragma unroll
      for (int m = 0; m < FM; m++)
#pragma unroll
        for (int n = 0; n < FN; n++) {
          acc[m][n] = mfma16(fa[m], fb[n], acc[m][n]);
          if constexpr (TERMS >= 2) acc[m][n] = mfma16(fal[m], fb[n], acc[m][n]);
          if constexpr (TERMS >= 3) acc[m][n] = mfma16(fa[m], fbl[n], acc[m][n]);
        }
    }
  };

  if constexpr (MODE == M_DBUF) {
    const int nIter = kend / BK;
    stage(0, 0);
    for (int it = 0; it < nIter; ++it) {
      __syncthreads();
      if (it + 1 < nIter) stage((it + 1) * BK, (it + 1) & 1);
      compute(it & 1);
    }
  } else {
    for (int k0 = 0; k0 < kend; k0 += BK) {
      __syncthreads();
      stage(k0, 0);
      __syncthreads();
      compute(0);
    }
  }

  // ---- epilogue ----  C/D layout: col = lane&15, row = (lane>>4)*4 + reg
#pragma unroll
  for (int m = 0; m < FM; m++) {
    const int grb = m0 + wm + m * 16 + fq * 4;
#pragma unroll
    for (int n = 0; n < FN; n++) {
      const int gc = n0 + wn + n * 16 + fr;
      if constexpr (EPI == EPI_F32) {
        float* o = p.outF + (size_t)z * p.sO;
#pragma unroll
        for (int r = 0; r < 4; r++)
          o[(size_t)(grb + r) * p.ldc + gc] = acc[m][n][r];
      } else if constexpr (EPI == EPI_SPLIT2) {
        const float bv = p.bias[gc];
#pragma unroll
        for (int r = 0; r < 4; r++) {
          const float v = acc[m][n][r] + bv;
          const h16 h = (h16)v;
          const h16 l = (h16)(v - (float)h);
          const size_t idx = (size_t)(grb + r) * 512;
          if (gc < 512) { p.oQh[idx + gc] = h; p.oQl[idx + gc] = l; }
          else          { p.oKh[idx + gc - 512] = h; p.oKl[idx + gc - 512] = l; }
        }
      } else if constexpr (EPI == EPI_VT) {
        const float bv = p.bias[gc];
        f16x4 pk;
#pragma unroll
        for (int r = 0; r < 4; r++) pk[r] = (h16)(acc[m][n][r] + bv);
        const int bb = grb >> 11;               // batch
        const int t  = grb & 2047;              // token (multiple of 4)
        *(f16x4*)(p.outH + ((size_t)bb * 512 + gc) * 2048 + t) = pk;
      } else { // EPI_H16
        h16* o = p.outH + (size_t)z * p.sO;
#pragma unroll
        for (int r = 0; r < 4; r++)
          o[(size_t)(grb + r) * p.ldc + gc] = (h16)acc[m][n][r];
      }
    }
  }
}

// Fused prep: split_x (8192 blocks) + prep_wqk (8192) + prep_wv (4096) +
// prep_projT (1024) = 21504 blocks, one launch. All independent, memory-bound.
__global__ __launch_bounds__(256) void prep_all(
    const float* __restrict__ x, h16* __restrict__ xh, h16* __restrict__ xl,
    const float* __restrict__ WQ, const float* __restrict__ bQ,
    const float* __restrict__ WK, const float* __restrict__ bK,
    h16* __restrict__ Wh, h16* __restrict__ Wl, float* __restrict__ bias_qk,
    const float* __restrict__ WV, const float* __restrict__ bV,
    h16* __restrict__ Wv, float* __restrict__ bias_v,
    const float* __restrict__ proj, h16* __restrict__ projT)
{
  const int b = blockIdx.x;
  if (b < 8192) {                       // ---- split_x ----
    const size_t i = ((size_t)b * 256 + threadIdx.x) * 8;
    const float4 a = *(const float4*)(x + i);
    const float4 c = *(const float4*)(x + i + 4);
    const float vv[8] = {a.x, a.y, a.z, a.w, c.x, c.y, c.z, c.w};
    f16x8 h, l;
#pragma unroll
    for (int j = 0; j < 8; j++) {
      const h16 hh = (h16)vv[j];
      h[j] = hh;
      l[j] = (h16)(vv[j] - (float)hh);
    }
    *(f16x8*)(xh + i) = h;
    *(f16x8*)(xl + i) = l;
  } else if (b < 16384) {               // ---- prep_wqk ----
    const int idx = (b - 8192) * 256 + threadIdx.x;
    const int n = idx >> 11;
    const int k = idx & 2047;
    float v;
    if (n < 512) {
      const int g = n >> 7, e = n & 127;
      const size_t base = (size_t)(128 * g + e) * 2048 + k;   // head 4j+g rows
      v = WQ[base] + WQ[base + (size_t)512 * 2048] + WQ[base + (size_t)1024 * 2048]
        + WQ[base + (size_t)1536 * 2048];
    } else {
      v = WK[(size_t)(n - 512) * 2048 + k];
    }
    const h16 h = (h16)v;
    Wh[idx] = h;
    Wl[idx] = (h16)(v - (float)h);
    if (k == 0) {
      if (n < 512) {
        const int g = n >> 7, e = n & 127;
        const int r = 128 * g + e;
        bias_qk[n] = bQ[r] + bQ[r + 512] + bQ[r + 1024] + bQ[r + 1536];
      } else {
        bias_qk[n] = bK[n - 512];
      }
    }
  } else if (b < 20480) {               // ---- prep_wv ----
    const int idx = (b - 16384) * 256 + threadIdx.x;
    Wv[idx] = (h16)WV[idx];
    if ((idx & 2047) == 0) bias_v[idx >> 11] = bV[idx >> 11];
  } else {                              // ---- prep_projT ----
    const int idx = (b - 20480) * 256 + threadIdx.x;
    const int n = idx >> 9;
    const int o = (idx & 511) << 2;
    const int g = n >> 7, e = n & 127;
    const size_t base = (size_t)(128 * g + e) * 2048 + o;
    const float4 a = *(const float4*)(proj + base);
    const float4 c = *(const float4*)(proj + base + (size_t)512 * 2048);
    const float4 d = *(const float4*)(proj + base + (size_t)1024 * 2048);
    const float4 f = *(const float4*)(proj + base + (size_t)1536 * 2048);
    projT[(size_t)(o + 0) * 512 + n] = (h16)(a.x + c.x + d.x + f.x);
    projT[(size_t)(o + 1) * 512 + n] = (h16)(a.y + c.y + d.y + f.y);
    projT[(size_t)(o + 2) * 512 + n] = (h16)(a.z + c.z + d.z + f.z);
    projT[(size_t)(o + 3) * 512 + n] = (h16)(a.w + c.w + d.w + f.w);
  }
}

// Batched causal row softmax; blockIdx.x = b*2048 + t. attn = softmax/sqrt(128).
__global__ __launch_bounds__(256) void softmax_row(const float* __restrict__ sc,
                                                   h16* __restrict__ attn)
{
  const int bt = blockIdx.x;
  const int t = bt & 2047;
  const int tid = threadIdx.x;
  const int lane = tid & 63;
  const int wid = tid >> 6;
  const int len = t + 1;
  const size_t rowoff = (size_t)bt * 2048;
  const float* row = sc + rowoff;
  const int c0 = tid * 8;
  float v[8];
  if (c0 < len) {
    const float4 a = *(const float4*)(row + c0);
    const float4 b = *(const float4*)(row + c0 + 4);
    v[0] = a.x; v[1] = a.y; v[2] = a.z; v[3] = a.w;
    v[4] = b.x; v[5] = b.y; v[6] = b.z; v[7] = b.w;
#pragma unroll
    for (int j = 0; j < 8; j++)
      if (c0 + j >= len) v[j] = -INFINITY;
  } else {
#pragma unroll
    for (int j = 0; j < 8; j++) v[j] = -INFINITY;
  }
  float m = v[0];
#pragma unroll
  for (int j = 1; j < 8; j++) m = fmaxf(m, v[j]);
#pragma unroll
  for (int off = 32; off > 0; off >>= 1) m = fmaxf(m, __shfl_xor(m, off));
  __shared__ float redm[4];
  if (lane == 0) redm[wid] = m;
  __syncthreads();
  m = fmaxf(fmaxf(redm[0], redm[1]), fmaxf(redm[2], redm[3]));
  float e[8];
  float s = 0.f;
#pragma unroll
  for (int j = 0; j < 8; j++) { e[j] = expf(v[j] - m); s += e[j]; }
#pragma unroll
  for (int off = 32; off > 0; off >>= 1) s += __shfl_xor(s, off);
  __shared__ float reds[4];
  if (lane == 0) reds[wid] = s;
  __syncthreads();
  s = reds[0] + reds[1] + reds[2] + reds[3];
  const float inv = 1.f / (s * 11.313708498984761f);   // * sqrt(128)
  const int tend = ((t >> 7) + 1) << 7;                // row's causal tile end
  if (c0 < tend) {
    f16x8 o;
#pragma unroll
    for (int j = 0; j < 8; j++) o[j] = (h16)(e[j] * inv);
    *(f16x8*)(attn + rowoff + c0) = o;
  }
}

extern "C" void kernel_launch(void* const* d_in, const int* in_sizes, int n_in,
                              void* d_out, int out_size, void* d_ws, size_t ws_size,
                              hipStream_t stream)
{
  (void)in_sizes; (void)n_in;
  const float* x    = (const float*)d_in[0];
  const float* WQ   = (const float*)d_in[1];
  const float* bQv  = (const float*)d_in[2];
  const float* WK   = (const float*)d_in[3];
  const float* bKv  = (const float*)d_in[4];
  const float* WV   = (const float*)d_in[5];
  const float* bVv  = (const float*)d_in[6];
  const float* proj = (const float*)d_in[7];
  float* out = (float*)d_out;

  char* ws = (char*)d_ws;
  size_t off = 0;
  auto alloc = [&](size_t bytes) -> void* {
    off = (off + 255) & ~(size_t)255;
    void* p = ws + off;
    off += bytes;
    return p;
  };
  // x split region (64MiB = xh+xl); 4-batch scores (64MiB fp32) aliases it after projections.
  char* xregion = (char*)alloc((size_t)2 * 16777216 * 2);
  h16* xh = (h16*)xregion;
  h16* xl = (h16*)(xregion + (size_t)16777216 * 2);
  float* scores = (float*)xregion;                       // [4][2048][2048] fp32
  h16* attn = (h16*)alloc((size_t)4 * 2048 * 2048 * 2);  // [4][2048][2048] fp16

  h16* Wqk_h = (h16*)alloc((size_t)1024 * 2048 * 2);
  h16* Wqk_l = (h16*)alloc((size_t)1024 * 2048 * 2);
  h16* Wv    = (h16*)alloc((size_t)512 * 2048 * 2);
  h16* projT = (h16*)alloc((size_t)2048 * 512 * 2);
  float* bias_qk = (float*)alloc(1024 * 4);
  float* bias_v  = (float*)alloc(512 * 4);
  h16* Qh = (h16*)alloc((size_t)8192 * 512 * 2);
  h16* Ql = (h16*)alloc((size_t)8192 * 512 * 2);
  h16* Kh = (h16*)alloc((size_t)8192 * 512 * 2);
  h16* Kl = (h16*)alloc((size_t)8192 * 512 * 2);
  h16* Vt = (h16*)alloc((size_t)4 * 512 * 2048 * 2);   // [b][d][t]
  h16* Zg = (h16*)alloc((size_t)8192 * 512 * 2);
  if (off > ws_size) {           // distinctive failure signal if ws too small
    hipMemsetAsync(d_out, 0x7F, (size_t)out_size * 4, stream);
    return;
  }

  prep_all<<<21504, 256, 0, stream>>>(x, xh, xl, WQ, bQv, WK, bKv, Wqk_h, Wqk_l,
                                      bias_qk, WV, bVv, Wv, bias_v, proj, projT);

  { // Qagg+K projection: 512t M_SINGLE (96us, MfmaUtil 51%)
    GP p{};
    p.Ah = xh; p.Al = xl; p.Bh = Wqk_h; p.Bl = Wqk_l; p.bias = bias_qk;
    p.oQh = Qh; p.oQl = Ql; p.oKh = Kh; p.oKl = Kl;
    p.K = 2048; p.lda = 2048; p.ldb = 2048; p.ldc = 0;
    gemm_bt<512, 128, 128, 1, 3, EPI_SPLIT2, false, false, M_SINGLE><<<dim3(8, 64, 1), 512, 0, stream>>>(p);
  }
  { // V projection (hi-only) -> Vt; 512t dbuf 48KB
    GP p{};
    p.Ah = xh; p.Bh = Wv; p.bias = bias_v; p.outH = Vt;
    p.K = 2048; p.lda = 2048; p.ldb = 2048; p.ldc = 0;
    gemm_bt<512, 128, 64, 0, 1, EPI_VT, false, false, M_DBUF><<<dim3(8, 64, 1), 512, 0, stream>>>(p);
  }
  // xh/xl dead from here; scores alias their storage.
  { // scores = Qagg @ K^T: 256t single-buffer, causal tile skip
    GP p{};
    p.Ah = Qh; p.Al = Ql; p.Bh = Kh; p.Bl = Kl; p.outF = scores;
    p.K = 512; p.lda = 512; p.ldb = 512; p.ldc = 2048;
    p.sA = (size_t)2048 * 512; p.sB = (size_t)2048 * 512; p.sO = (size_t)2048 * 2048;
    gemm_bt<256, 128, 128, 1, 3, EPI_F32, true, false, M_SINGLE><<<dim3(16, 16, 4), 256, 0, stream>>>(p);
  }
  softmax_row<<<8192, 256, 0, stream>>>(scores, attn);
  { // Zg = attn @ Vt^T: 512t dbuf 48KB klim
    GP p{};
    p.Ah = attn; p.Bh = Vt; p.outH = Zg;
    p.K = 2048; p.lda = 2048; p.ldb = 2048; p.ldc = 512;
    p.sA = (size_t)2048 * 2048; p.sB = (size_t)512 * 2048; p.sO = (size_t)2048 * 512;
    gemm_bt<512, 128, 64, 0, 1, EPI_H16, false, true, M_DBUF><<<dim3(8, 16, 4), 512, 0, stream>>>(p);
  }
  { // out = Zg @ projAgg: 256t dbuf 64KB
    GP p{};
    p.Ah = Zg; p.Bh = projT; p.outF = out;
    p.K = 512; p.lda = 512; p.ldb = 512; p.ldc = 2048;
    gemm_bt<256, 128, 128, 0, 1, EPI_F32, false, false, M_DBUF><<<dim3(16, 64, 1), 256, 0, stream>>>(p);
  }
}

// Round 32
// 269.141 us; speedup vs baseline: 1.0234x; 1.0114x over previous
//
#include <hip/hip_runtime.h>
#include <math.h>

typedef _Float16 h16;
typedef _Float16 f16x8 __attribute__((ext_vector_type(8)));
typedef _Float16 f16x4 __attribute__((ext_vector_type(4)));
typedef float f32x4 __attribute__((ext_vector_type(4)));

enum { EPI_F32 = 0, EPI_SPLIT2 = 1, EPI_VT = 2, EPI_H16 = 3 };
enum { M_SINGLE = 0, M_DBUF = 1 };

struct GP {
  const h16* Ah; const h16* Al;
  const h16* Bh; const h16* Bl;
  const float* bias;
  float* outF;
  h16* oQh; h16* oQl; h16* oKh; h16* oKl;
  h16* outH;
  int K, lda, ldb, ldc;
  size_t sA, sB, sO;          // per-batch (blockIdx.z) element strides
};

__device__ __forceinline__ f32x4 mfma16(f16x8 a, f16x8 b, f32x4 c) {
  return __builtin_amdgcn_mfma_f32_16x16x32_f16(a, b, c, 0, 0, 0);
}

// async global->LDS, 16B per lane; LDS dest = wave-uniform base + lane*16
__device__ __forceinline__ void glds16(const h16* g, h16* l) {
  __builtin_amdgcn_global_load_lds((const __attribute__((address_space(1))) void*)g,
                                   (__attribute__((address_space(3))) void*)l,
                                   16, 0, 0);
}

// C[M,N] = A[M,K] @ B[N,K]^T (both K-contiguous fp16), fp32 accum.
// TERMS: 1 = AhBh; 2 = +AlBh; 3 = +AhBl.  BSPL: B has lo part.
// BK=64; T2 swizzle, linear LDS dest (rule #21): src col (lane&7)^(lane>>3),
// read (ks*4+fq)^(fr&7) -> 0 bank conflicts (measured r10).
// FINAL CONFIG (r28-r31, measured 271.5/272.4/275.4/272.2us; space closed r15-r26):
//   QK: 512t M_SINGLE (96us, MfmaUtil 51%; beats 256t/BN64/dbuf128K/M_PIPE/dbufBK32)
//   V-proj, PV: 512t M_DBUF 48KB (long/medium-K)
//   scores, outproj: 256t (short-K regresses at 512t r17/r19 and dbufBK32 r26)
//   prep_all: full fusion incl. split_x (r28: -7us vs split launches)
// XCD-chunked swizzle (T1) needs nwg%8==0.
template<int BLK, int BM, int BN, int BSPL, int TERMS, int EPI, bool CSKIP, bool KLIM, int MODE>
__global__ __launch_bounds__(BLK, (BLK == 512 ? 4 : 2)) void gemm_bt(GP p)
{
  constexpr int BK = 64;
  constexpr bool ASPL = (TERMS >= 2);
  constexpr int NW = BLK / 64;                // waves per block
  constexpr int WR = 2, WC = NW / 2;          // wave grid rows x cols
  constexpr int WM = BM / WR, WN = BN / WC;   // per-wave output tile
  constexpr int FM = WM / 16, FN = WN / 16;
  constexpr int AH = BM * BK, BH = BN * BK;   // per-half LDS elements

  const int gx = gridDim.x, gy = gridDim.y;
  int lin = blockIdx.x + gx * blockIdx.y;
  const int nwg = gx * gy;
  if ((nwg & 7) == 0) lin = (lin & 7) * (nwg >> 3) + (lin >> 3);
  const int m0 = (lin / gx) * BM;
  const int n0 = (lin % gx) * BN;
  if (CSKIP && n0 >= m0 + BM) return;         // tile fully above causal diagonal
  const int z = blockIdx.z;
  const h16* Ah = p.Ah + (size_t)z * p.sA;
  const h16* Al = ASPL ? p.Al + (size_t)z * p.sA : (const h16*)nullptr;
  const h16* Bh = p.Bh + (size_t)z * p.sB;
  const h16* Bl = BSPL ? p.Bl + (size_t)z * p.sB : (const h16*)nullptr;

  constexpr int NBUF = (MODE == M_SINGLE) ? 1 : 2;
  __shared__ h16 sAh[NBUF * AH];
  __shared__ h16 sAl[ASPL ? NBUF * AH : 8];
  __shared__ h16 sBh[NBUF * BH];
  __shared__ h16 sBl[BSPL ? NBUF * BH : 8];

  const int tid = threadIdx.x;
  const int lane = tid & 63;
  const int w = tid >> 6;
  const int wm = (w / WC) * WM;
  const int wn = (w % WC) * WN;
  const int fr = lane & 15;
  const int fq = lane >> 4;
  const int lrow = lane >> 3;                        // 0..7: row within 8-row chunk
  const int lcol = (((lane & 7) ^ lrow) * 8);        // swizzled global col (h16 units)

  f32x4 acc[FM][FN];
#pragma unroll
  for (int i = 0; i < FM; i++)
#pragma unroll
    for (int j = 0; j < FN; j++) acc[i][j] = f32x4{0.f, 0.f, 0.f, 0.f};

  const int kend = KLIM ? ((m0 + BM < p.K) ? (m0 + BM) : p.K) : p.K;

  auto stage = [&](int k0, int half) {
    const int ao = half * AH, bo = half * BH;
#pragma unroll
    for (int i = w; i < BM / 8; i += NW)
      glds16(Ah + (size_t)(m0 + i * 8 + lrow) * p.lda + (k0 + lcol), &sAh[ao + i * 512]);
    if constexpr (ASPL) {
#pragma unroll
      for (int i = w; i < BM / 8; i += NW)
        glds16(Al + (size_t)(m0 + i * 8 + lrow) * p.lda + (k0 + lcol), &sAl[ao + i * 512]);
    }
#pragma unroll
    for (int i = w; i < BN / 8; i += NW)
      glds16(Bh + (size_t)(n0 + i * 8 + lrow) * p.ldb + (k0 + lcol), &sBh[bo + i * 512]);
    if constexpr (BSPL) {
#pragma unroll
      for (int i = w; i < BN / 8; i += NW)
        glds16(Bl + (size_t)(n0 + i * 8 + lrow) * p.ldb + (k0 + lcol), &sBl[bo + i * 512]);
    }
  };

  auto compute = [&](int half) {
    const int ca = half * AH, cb = half * BH;
#pragma unroll
    for (int ks = 0; ks < 2; ks++) {
      const int swo = (((ks * 4 + fq) ^ (fr & 7)) * 8);   // un-swizzled read offset
      f16x8 fa[FM], fb[FN];
      f16x8 fal[ASPL ? FM : 1], fbl[BSPL ? FN : 1];
#pragma unroll
      for (int m = 0; m < FM; m++) {
        fa[m] = *(const f16x8*)&sAh[ca + (wm + m * 16 + fr) * BK + swo];
        if constexpr (ASPL)
          fal[m] = *(const f16x8*)&sAl[ca + (wm + m * 16 + fr) * BK + swo];
      }
#pragma unroll
      for (int n = 0; n < FN; n++) {
        fb[n] = *(const f16x8*)&sBh[cb + (wn + n * 16 + fr) * BK + swo];
        if constexpr (BSPL)
          fbl[n] = *(const f16x8*)&sBl[cb + (wn + n * 16 + fr) * BK + swo];
      }
#pragma unroll
      for (int m = 0; m < FM; m++)
#pragma unroll
        for (int n = 0; n < FN; n++) {
          acc[m][n] = mfma16(fa[m], fb[n], acc[m][n]);
          if constexpr (TERMS >= 2) acc[m][n] = mfma16(fal[m], fb[n], acc[m][n]);
          if constexpr (TERMS >= 3) acc[m][n] = mfma16(fa[m], fbl[n], acc[m][n]);
        }
    }
  };

  if constexpr (MODE == M_DBUF) {
    const int nIter = kend / BK;
    stage(0, 0);
    for (int it = 0; it < nIter; ++it) {
      __syncthreads();
      if (it + 1 < nIter) stage((it + 1) * BK, (it + 1) & 1);
      compute(it & 1);
    }
  } else {
    for (int k0 = 0; k0 < kend; k0 += BK) {
      __syncthreads();
      stage(k0, 0);
      __syncthreads();
      compute(0);
    }
  }

  // ---- epilogue ----  C/D layout: col = lane&15, row = (lane>>4)*4 + reg
#pragma unroll
  for (int m = 0; m < FM; m++) {
    const int grb = m0 + wm + m * 16 + fq * 4;
#pragma unroll
    for (int n = 0; n < FN; n++) {
      const int gc = n0 + wn + n * 16 + fr;
      if constexpr (EPI == EPI_F32) {
        float* o = p.outF + (size_t)z * p.sO;
#pragma unroll
        for (int r = 0; r < 4; r++)
          o[(size_t)(grb + r) * p.ldc + gc] = acc[m][n][r];
      } else if constexpr (EPI == EPI_SPLIT2) {
        const float bv = p.bias[gc];
#pragma unroll
        for (int r = 0; r < 4; r++) {
          const float v = acc[m][n][r] + bv;
          const h16 h = (h16)v;
          const h16 l = (h16)(v - (float)h);
          const size_t idx = (size_t)(grb + r) * 512;
          if (gc < 512) { p.oQh[idx + gc] = h; p.oQl[idx + gc] = l; }
          else          { p.oKh[idx + gc - 512] = h; p.oKl[idx + gc - 512] = l; }
        }
      } else if constexpr (EPI == EPI_VT) {
        const float bv = p.bias[gc];
        f16x4 pk;
#pragma unroll
        for (int r = 0; r < 4; r++) pk[r] = (h16)(acc[m][n][r] + bv);
        const int bb = grb >> 11;               // batch
        const int t  = grb & 2047;              // token (multiple of 4)
        *(f16x4*)(p.outH + ((size_t)bb * 512 + gc) * 2048 + t) = pk;
      } else { // EPI_H16
        h16* o = p.outH + (size_t)z * p.sO;
#pragma unroll
        for (int r = 0; r < 4; r++)
          o[(size_t)(grb + r) * p.ldc + gc] = (h16)acc[m][n][r];
      }
    }
  }
}

// Fused prep: split_x (8192 blocks) + prep_wqk (8192) + prep_wv (4096) +
// prep_projT (1024) = 21504 blocks, one launch. All independent, memory-bound.
__global__ __launch_bounds__(256) void prep_all(
    const float* __restrict__ x, h16* __restrict__ xh, h16* __restrict__ xl,
    const float* __restrict__ WQ, const float* __restrict__ bQ,
    const float* __restrict__ WK, const float* __restrict__ bK,
    h16* __restrict__ Wh, h16* __restrict__ Wl, float* __restrict__ bias_qk,
    const float* __restrict__ WV, const float* __restrict__ bV,
    h16* __restrict__ Wv, float* __restrict__ bias_v,
    const float* __restrict__ proj, h16* __restrict__ projT)
{
  const int b = blockIdx.x;
  if (b < 8192) {                       // ---- split_x ----
    const size_t i = ((size_t)b * 256 + threadIdx.x) * 8;
    const float4 a = *(const float4*)(x + i);
    const float4 c = *(const float4*)(x + i + 4);
    const float vv[8] = {a.x, a.y, a.z, a.w, c.x, c.y, c.z, c.w};
    f16x8 h, l;
#pragma unroll
    for (int j = 0; j < 8; j++) {
      const h16 hh = (h16)vv[j];
      h[j] = hh;
      l[j] = (h16)(vv[j] - (float)hh);
    }
    *(f16x8*)(xh + i) = h;
    *(f16x8*)(xl + i) = l;
  } else if (b < 16384) {               // ---- prep_wqk ----
    const int idx = (b - 8192) * 256 + threadIdx.x;
    const int n = idx >> 11;
    const int k = idx & 2047;
    float v;
    if (n < 512) {
      const int g = n >> 7, e = n & 127;
      const size_t base = (size_t)(128 * g + e) * 2048 + k;   // head 4j+g rows
      v = WQ[base] + WQ[base + (size_t)512 * 2048] + WQ[base + (size_t)1024 * 2048]
        + WQ[base + (size_t)1536 * 2048];
    } else {
      v = WK[(size_t)(n - 512) * 2048 + k];
    }
    const h16 h = (h16)v;
    Wh[idx] = h;
    Wl[idx] = (h16)(v - (float)h);
    if (k == 0) {
      if (n < 512) {
        const int g = n >> 7, e = n & 127;
        const int r = 128 * g + e;
        bias_qk[n] = bQ[r] + bQ[r + 512] + bQ[r + 1024] + bQ[r + 1536];
      } else {
        bias_qk[n] = bK[n - 512];
      }
    }
  } else if (b < 20480) {               // ---- prep_wv ----
    const int idx = (b - 16384) * 256 + threadIdx.x;
    Wv[idx] = (h16)WV[idx];
    if ((idx & 2047) == 0) bias_v[idx >> 11] = bV[idx >> 11];
  } else {                              // ---- prep_projT ----
    const int idx = (b - 20480) * 256 + threadIdx.x;
    const int n = idx >> 9;
    const int o = (idx & 511) << 2;
    const int g = n >> 7, e = n & 127;
    const size_t base = (size_t)(128 * g + e) * 2048 + o;
    const float4 a = *(const float4*)(proj + base);
    const float4 c = *(const float4*)(proj + base + (size_t)512 * 2048);
    const float4 d = *(const float4*)(proj + base + (size_t)1024 * 2048);
    const float4 f = *(const float4*)(proj + base + (size_t)1536 * 2048);
    projT[(size_t)(o + 0) * 512 + n] = (h16)(a.x + c.x + d.x + f.x);
    projT[(size_t)(o + 1) * 512 + n] = (h16)(a.y + c.y + d.y + f.y);
    projT[(size_t)(o + 2) * 512 + n] = (h16)(a.z + c.z + d.z + f.z);
    projT[(size_t)(o + 3) * 512 + n] = (h16)(a.w + c.w + d.w + f.w);
  }
}

// Batched causal row softmax; blockIdx.x = b*2048 + t. attn = softmax/sqrt(128).
__global__ __launch_bounds__(256) void softmax_row(const float* __restrict__ sc,
                                                   h16* __restrict__ attn)
{
  const int bt = blockIdx.x;
  const int t = bt & 2047;
  const int tid = threadIdx.x;
  const int lane = tid & 63;
  const int wid = tid >> 6;
  const int len = t + 1;
  const size_t rowoff = (size_t)bt * 2048;
  const float* row = sc + rowoff;
  const int c0 = tid * 8;
  float v[8];
  if (c0 < len) {
    const float4 a = *(const float4*)(row + c0);
    const float4 b = *(const float4*)(row + c0 + 4);
    v[0] = a.x; v[1] = a.y; v[2] = a.z; v[3] = a.w;
    v[4] = b.x; v[5] = b.y; v[6] = b.z; v[7] = b.w;
#pragma unroll
    for (int j = 0; j < 8; j++)
      if (c0 + j >= len) v[j] = -INFINITY;
  } else {
#pragma unroll
    for (int j = 0; j < 8; j++) v[j] = -INFINITY;
  }
  float m = v[0];
#pragma unroll
  for (int j = 1; j < 8; j++) m = fmaxf(m, v[j]);
#pragma unroll
  for (int off = 32; off > 0; off >>= 1) m = fmaxf(m, __shfl_xor(m, off));
  __shared__ float redm[4];
  if (lane == 0) redm[wid] = m;
  __syncthreads();
  m = fmaxf(fmaxf(redm[0], redm[1]), fmaxf(redm[2], redm[3]));
  float e[8];
  float s = 0.f;
#pragma unroll
  for (int j = 0; j < 8; j++) { e[j] = expf(v[j] - m); s += e[j]; }
#pragma unroll
  for (int off = 32; off > 0; off >>= 1) s += __shfl_xor(s, off);
  __shared__ float reds[4];
  if (lane == 0) reds[wid] = s;
  __syncthreads();
  s = reds[0] + reds[1] + reds[2] + reds[3];
  const float inv = 1.f / (s * 11.313708498984761f);   // * sqrt(128)
  const int tend = ((t >> 7) + 1) << 7;                // row's causal tile end
  if (c0 < tend) {
    f16x8 o;
#pragma unroll
    for (int j = 0; j < 8; j++) o[j] = (h16)(e[j] * inv);
    *(f16x8*)(attn + rowoff + c0) = o;
  }
}

extern "C" void kernel_launch(void* const* d_in, const int* in_sizes, int n_in,
                              void* d_out, int out_size, void* d_ws, size_t ws_size,
                              hipStream_t stream)
{
  (void)in_sizes; (void)n_in;
  const float* x    = (const float*)d_in[0];
  const float* WQ   = (const float*)d_in[1];
  const float* bQv  = (const float*)d_in[2];
  const float* WK   = (const float*)d_in[3];
  const float* bKv  = (const float*)d_in[4];
  const float* WV   = (const float*)d_in[5];
  const float* bVv  = (const float*)d_in[6];
  const float* proj = (const float*)d_in[7];
  float* out = (float*)d_out;

  char* ws = (char*)d_ws;
  size_t off = 0;
  auto alloc = [&](size_t bytes) -> void* {
    off = (off + 255) & ~(size_t)255;
    void* p = ws + off;
    off += bytes;
    return p;
  };
  // x split region (64MiB = xh+xl); 4-batch scores (64MiB fp32) aliases it after projections.
  char* xregion = (char*)alloc((size_t)2 * 16777216 * 2);
  h16* xh = (h16*)xregion;
  h16* xl = (h16*)(xregion + (size_t)16777216 * 2);
  float* scores = (float*)xregion;                       // [4][2048][2048] fp32
  h16* attn = (h16*)alloc((size_t)4 * 2048 * 2048 * 2);  // [4][2048][2048] fp16

  h16* Wqk_h = (h16*)alloc((size_t)1024 * 2048 * 2);
  h16* Wqk_l = (h16*)alloc((size_t)1024 * 2048 * 2);
  h16* Wv    = (h16*)alloc((size_t)512 * 2048 * 2);
  h16* projT = (h16*)alloc((size_t)2048 * 512 * 2);
  float* bias_qk = (float*)alloc(1024 * 4);
  float* bias_v  = (float*)alloc(512 * 4);
  h16* Qh = (h16*)alloc((size_t)8192 * 512 * 2);
  h16* Ql = (h16*)alloc((size_t)8192 * 512 * 2);
  h16* Kh = (h16*)alloc((size_t)8192 * 512 * 2);
  h16* Kl = (h16*)alloc((size_t)8192 * 512 * 2);
  h16* Vt = (h16*)alloc((size_t)4 * 512 * 2048 * 2);   // [b][d][t]
  h16* Zg = (h16*)alloc((size_t)8192 * 512 * 2);
  if (off > ws_size) {           // distinctive failure signal if ws too small
    hipMemsetAsync(d_out, 0x7F, (size_t)out_size * 4, stream);
    return;
  }

  prep_all<<<21504, 256, 0, stream>>>(x, xh, xl, WQ, bQv, WK, bKv, Wqk_h, Wqk_l,
                                      bias_qk, WV, bVv, Wv, bias_v, proj, projT);

  { // Qagg+K projection: 512t M_SINGLE (96us, MfmaUtil 51%)
    GP p{};
    p.Ah = xh; p.Al = xl; p.Bh = Wqk_h; p.Bl = Wqk_l; p.bias = bias_qk;
    p.oQh = Qh; p.oQl = Ql; p.oKh = Kh; p.oKl = Kl;
    p.K = 2048; p.lda = 2048; p.ldb = 2048; p.ldc = 0;
    gemm_bt<512, 128, 128, 1, 3, EPI_SPLIT2, false, false, M_SINGLE><<<dim3(8, 64, 1), 512, 0, stream>>>(p);
  }
  { // V projection (hi-only) -> Vt; 512t dbuf 48KB
    GP p{};
    p.Ah = xh; p.Bh = Wv; p.bias = bias_v; p.outH = Vt;
    p.K = 2048; p.lda = 2048; p.ldb = 2048; p.ldc = 0;
    gemm_bt<512, 128, 64, 0, 1, EPI_VT, false, false, M_DBUF><<<dim3(8, 64, 1), 512, 0, stream>>>(p);
  }
  // xh/xl dead from here; scores alias their storage.
  { // scores = Qagg @ K^T: 256t single-buffer, causal tile skip
    GP p{};
    p.Ah = Qh; p.Al = Ql; p.Bh = Kh; p.Bl = Kl; p.outF = scores;
    p.K = 512; p.lda = 512; p.ldb = 512; p.ldc = 2048;
    p.sA = (size_t)2048 * 512; p.sB = (size_t)2048 * 512; p.sO = (size_t)2048 * 2048;
    gemm_bt<256, 128, 128, 1, 3, EPI_F32, true, false, M_SINGLE><<<dim3(16, 16, 4), 256, 0, stream>>>(p);
  }
  softmax_row<<<8192, 256, 0, stream>>>(scores, attn);
  { // Zg = attn @ Vt^T: 512t dbuf 48KB klim
    GP p{};
    p.Ah = attn; p.Bh = Vt; p.outH = Zg;
    p.K = 2048; p.lda = 2048; p.ldb = 2048; p.ldc = 512;
    p.sA = (size_t)2048 * 2048; p.sB = (size_t)512 * 2048; p.sO = (size_t)2048 * 512;
    gemm_bt<512, 128, 64, 0, 1, EPI_H16, false, true, M_DBUF><<<dim3(8, 16, 4), 512, 0, stream>>>(p);
  }
  { // out = Zg @ projAgg: 256t dbuf 64KB
    GP p{};
    p.Ah = Zg; p.Bh = projT; p.outF = out;
    p.K = 512; p.lda = 512; p.ldb = 512; p.ldc = 2048;
    gemm_bt<256, 128, 128, 0, 1, EPI_F32, false, false, M_DBUF><<<dim3(16, 64, 1), 256, 0, stream>>>(p);
  }
}

// Round 33
// 268.543 us; speedup vs baseline: 1.0256x; 1.0022x over previous
//
#include <hip/hip_runtime.h>
#include <math.h>

typedef _Float16 h16;
typedef _Float16 f16x8 __attribute__((ext_vector_type(8)));
typedef _Float16 f16x4 __attribute__((ext_vector_type(4)));
typedef float f32x4 __attribute__((ext_vector_type(4)));

enum { EPI_F32 = 0, EPI_SPLIT2 = 1, EPI_VT = 2, EPI_H16 = 3 };
enum { M_SINGLE = 0, M_DBUF = 1 };

struct GP {
  const h16* Ah; const h16* Al;
  const h16* Bh; const h16* Bl;
  const float* bias;
  float* outF;
  h16* oQh; h16* oQl; h16* oKh; h16* oKl;
  h16* outH;
  int K, lda, ldb, ldc;
  size_t sA, sB, sO;          // per-batch (blockIdx.z) element strides
};

__device__ __forceinline__ f32x4 mfma16(f16x8 a, f16x8 b, f32x4 c) {
  return __builtin_amdgcn_mfma_f32_16x16x32_f16(a, b, c, 0, 0, 0);
}

// async global->LDS, 16B per lane; LDS dest = wave-uniform base + lane*16
__device__ __forceinline__ void glds16(const h16* g, h16* l) {
  __builtin_amdgcn_global_load_lds((const __attribute__((address_space(1))) void*)g,
                                   (__attribute__((address_space(3))) void*)l,
                                   16, 0, 0);
}

// C[M,N] = A[M,K] @ B[N,K]^T (both K-contiguous fp16), fp32 accum.
// TERMS: 1 = AhBh; 2 = +AlBh; 3 = +AhBl.  BSPL: B has lo part.
// BK=64; T2 swizzle, linear LDS dest (rule #21): src col (lane&7)^(lane>>3),
// read (ks*4+fq)^(fr&7) -> 0 bank conflicts (measured r10).
// FINAL CONFIG (r28-r32, measured 271.5/272.4/275.4/272.2/269.1us):
//   QK: 512t M_SINGLE (96us, MfmaUtil 51%; beats 256t/BN64/dbuf128K/M_PIPE/dbufBK32)
//   V-proj, PV: 512t M_DBUF 48KB (long/medium-K)
//   scores, outproj: 256t (short-K regresses at 512t r17/r19 and dbufBK32 r26)
//   prep_all: full fusion incl. split_x (r28: -7us vs split launches)
// XCD-chunked swizzle (T1) needs nwg%8==0.
template<int BLK, int BM, int BN, int BSPL, int TERMS, int EPI, bool CSKIP, bool KLIM, int MODE>
__global__ __launch_bounds__(BLK, (BLK == 512 ? 4 : 2)) void gemm_bt(GP p)
{
  constexpr int BK = 64;
  constexpr bool ASPL = (TERMS >= 2);
  constexpr int NW = BLK / 64;                // waves per block
  constexpr int WR = 2, WC = NW / 2;          // wave grid rows x cols
  constexpr int WM = BM / WR, WN = BN / WC;   // per-wave output tile
  constexpr int FM = WM / 16, FN = WN / 16;
  constexpr int AH = BM * BK, BH = BN * BK;   // per-half LDS elements

  const int gx = gridDim.x, gy = gridDim.y;
  int lin = blockIdx.x + gx * blockIdx.y;
  const int nwg = gx * gy;
  if ((nwg & 7) == 0) lin = (lin & 7) * (nwg >> 3) + (lin >> 3);
  const int m0 = (lin / gx) * BM;
  const int n0 = (lin % gx) * BN;
  if (CSKIP && n0 >= m0 + BM) return;         // tile fully above causal diagonal
  const int z = blockIdx.z;
  const h16* Ah = p.Ah + (size_t)z * p.sA;
  const h16* Al = ASPL ? p.Al + (size_t)z * p.sA : (const h16*)nullptr;
  const h16* Bh = p.Bh + (size_t)z * p.sB;
  const h16* Bl = BSPL ? p.Bl + (size_t)z * p.sB : (const h16*)nullptr;

  constexpr int NBUF = (MODE == M_SINGLE) ? 1 : 2;
  __shared__ h16 sAh[NBUF * AH];
  __shared__ h16 sAl[ASPL ? NBUF * AH : 8];
  __shared__ h16 sBh[NBUF * BH];
  __shared__ h16 sBl[BSPL ? NBUF * BH : 8];

  const int tid = threadIdx.x;
  const int lane = tid & 63;
  const int w = tid >> 6;
  const int wm = (w / WC) * WM;
  const int wn = (w % WC) * WN;
  const int fr = lane & 15;
  const int fq = lane >> 4;
  const int lrow = lane >> 3;                        // 0..7: row within 8-row chunk
  const int lcol = (((lane & 7) ^ lrow) * 8);        // swizzled global col (h16 units)

  f32x4 acc[FM][FN];
#pragma unroll
  for (int i = 0; i < FM; i++)
#pragma unroll
    for (int j = 0; j < FN; j++) acc[i][j] = f32x4{0.f, 0.f, 0.f, 0.f};

  const int kend = KLIM ? ((m0 + BM < p.K) ? (m0 + BM) : p.K) : p.K;

  auto stage = [&](int k0, int half) {
    const int ao = half * AH, bo = half * BH;
#pragma unroll
    for (int i = w; i < BM / 8; i += NW)
      glds16(Ah + (size_t)(m0 + i * 8 + lrow) * p.lda + (k0 + lcol), &sAh[ao + i * 512]);
    if constexpr (ASPL) {
#pragma unroll
      for (int i = w; i < BM / 8; i += NW)
        glds16(Al + (size_t)(m0 + i * 8 + lrow) * p.lda + (k0 + lcol), &sAl[ao + i * 512]);
    }
#pragma unroll
    for (int i = w; i < BN / 8; i += NW)
      glds16(Bh + (size_t)(n0 + i * 8 + lrow) * p.ldb + (k0 + lcol), &sBh[bo + i * 512]);
    if constexpr (BSPL) {
#pragma unroll
      for (int i = w; i < BN / 8; i += NW)
        glds16(Bl + (size_t)(n0 + i * 8 + lrow) * p.ldb + (k0 + lcol), &sBl[bo + i * 512]);
    }
  };

  auto compute = [&](int half) {
    const int ca = half * AH, cb = half * BH;
#pragma unroll
    for (int ks = 0; ks < 2; ks++) {
      const int swo = (((ks * 4 + fq) ^ (fr & 7)) * 8);   // un-swizzled read offset
      f16x8 fa[FM], fb[FN];
      f16x8 fal[ASPL ? FM : 1], fbl[BSPL ? FN : 1];
#pragma unroll
      for (int m = 0; m < FM; m++) {
        fa[m] = *(const f16x8*)&sAh[ca + (wm + m * 16 + fr) * BK + swo];
        if constexpr (ASPL)
          fal[m] = *(const f16x8*)&sAl[ca + (wm + m * 16 + fr) * BK + swo];
      }
#pragma unroll
      for (int n = 0; n < FN; n++) {
        fb[n] = *(const f16x8*)&sBh[cb + (wn + n * 16 + fr) * BK + swo];
        if constexpr (BSPL)
          fbl[n] = *(const f16x8*)&sBl[cb + (wn + n * 16 + fr) * BK + swo];
      }
#pragma unroll
      for (int m = 0; m < FM; m++)
#pragma unroll
        for (int n = 0; n < FN; n++) {
          acc[m][n] = mfma16(fa[m], fb[n], acc[m][n]);
          if constexpr (TERMS >= 2) acc[m][n] = mfma16(fal[m], fb[n], acc[m][n]);
          if constexpr (TERMS >= 3) acc[m][n] = mfma16(fa[m], fbl[n], acc[m][n]);
        }
    }
  };

  if constexpr (MODE == M_DBUF) {
    const int nIter = kend / BK;
    stage(0, 0);
    for (int it = 0; it < nIter; ++it) {
      __syncthreads();
      if (it + 1 < nIter) stage((it + 1) * BK, (it + 1) & 1);
      compute(it & 1);
    }
  } else {
    for (int k0 = 0; k0 < kend; k0 += BK) {
      __syncthreads();
      stage(k0, 0);
      __syncthreads();
      compute(0);
    }
  }

  // ---- epilogue ----  C/D layout: col = lane&15, row = (lane>>4)*4 + reg
#pragma unroll
  for (int m = 0; m < FM; m++) {
    const int grb = m0 + wm + m * 16 + fq * 4;
#pragma unroll
    for (int n = 0; n < FN; n++) {
      const int gc = n0 + wn + n * 16 + fr;
      if constexpr (EPI == EPI_F32) {
        float* o = p.outF + (size_t)z * p.sO;
#pragma unroll
        for (int r = 0; r < 4; r++)
          o[(size_t)(grb + r) * p.ldc + gc] = acc[m][n][r];
      } else if constexpr (EPI == EPI_SPLIT2) {
        const float bv = p.bias[gc];
#pragma unroll
        for (int r = 0; r < 4; r++) {
          const float v = acc[m][n][r] + bv;
          const h16 h = (h16)v;
          const h16 l = (h16)(v - (float)h);
          const size_t idx = (size_t)(grb + r) * 512;
          if (gc < 512) { p.oQh[idx + gc] = h; p.oQl[idx + gc] = l; }
          else          { p.oKh[idx + gc - 512] = h; p.oKl[idx + gc - 512] = l; }
        }
      } else if constexpr (EPI == EPI_VT) {
        const float bv = p.bias[gc];
        f16x4 pk;
#pragma unroll
        for (int r = 0; r < 4; r++) pk[r] = (h16)(acc[m][n][r] + bv);
        const int bb = grb >> 11;               // batch
        const int t  = grb & 2047;              // token (multiple of 4)
        *(f16x4*)(p.outH + ((size_t)bb * 512 + gc) * 2048 + t) = pk;
      } else { // EPI_H16
        h16* o = p.outH + (size_t)z * p.sO;
#pragma unroll
        for (int r = 0; r < 4; r++)
          o[(size_t)(grb + r) * p.ldc + gc] = (h16)acc[m][n][r];
      }
    }
  }
}

// Fused prep: split_x (8192 blocks) + prep_wqk (8192) + prep_wv (4096) +
// prep_projT (1024) = 21504 blocks, one launch. All independent, memory-bound.
__global__ __launch_bounds__(256) void prep_all(
    const float* __restrict__ x, h16* __restrict__ xh, h16* __restrict__ xl,
    const float* __restrict__ WQ, const float* __restrict__ bQ,
    const float* __restrict__ WK, const float* __restrict__ bK,
    h16* __restrict__ Wh, h16* __restrict__ Wl, float* __restrict__ bias_qk,
    const float* __restrict__ WV, const float* __restrict__ bV,
    h16* __restrict__ Wv, float* __restrict__ bias_v,
    const float* __restrict__ proj, h16* __restrict__ projT)
{
  const int b = blockIdx.x;
  if (b < 8192) {                       // ---- split_x ----
    const size_t i = ((size_t)b * 256 + threadIdx.x) * 8;
    const float4 a = *(const float4*)(x + i);
    const float4 c = *(const float4*)(x + i + 4);
    const float vv[8] = {a.x, a.y, a.z, a.w, c.x, c.y, c.z, c.w};
    f16x8 h, l;
#pragma unroll
    for (int j = 0; j < 8; j++) {
      const h16 hh = (h16)vv[j];
      h[j] = hh;
      l[j] = (h16)(vv[j] - (float)hh);
    }
    *(f16x8*)(xh + i) = h;
    *(f16x8*)(xl + i) = l;
  } else if (b < 16384) {               // ---- prep_wqk ----
    const int idx = (b - 8192) * 256 + threadIdx.x;
    const int n = idx >> 11;
    const int k = idx & 2047;
    float v;
    if (n < 512) {
      const int g = n >> 7, e = n & 127;
      const size_t base = (size_t)(128 * g + e) * 2048 + k;   // head 4j+g rows
      v = WQ[base] + WQ[base + (size_t)512 * 2048] + WQ[base + (size_t)1024 * 2048]
        + WQ[base + (size_t)1536 * 2048];
    } else {
      v = WK[(size_t)(n - 512) * 2048 + k];
    }
    const h16 h = (h16)v;
    Wh[idx] = h;
    Wl[idx] = (h16)(v - (float)h);
    if (k == 0) {
      if (n < 512) {
        const int g = n >> 7, e = n & 127;
        const int r = 128 * g + e;
        bias_qk[n] = bQ[r] + bQ[r + 512] + bQ[r + 1024] + bQ[r + 1536];
      } else {
        bias_qk[n] = bK[n - 512];
      }
    }
  } else if (b < 20480) {               // ---- prep_wv ----
    const int idx = (b - 16384) * 256 + threadIdx.x;
    Wv[idx] = (h16)WV[idx];
    if ((idx & 2047) == 0) bias_v[idx >> 11] = bV[idx >> 11];
  } else {                              // ---- prep_projT ----
    const int idx = (b - 20480) * 256 + threadIdx.x;
    const int n = idx >> 9;
    const int o = (idx & 511) << 2;
    const int g = n >> 7, e = n & 127;
    const size_t base = (size_t)(128 * g + e) * 2048 + o;
    const float4 a = *(const float4*)(proj + base);
    const float4 c = *(const float4*)(proj + base + (size_t)512 * 2048);
    const float4 d = *(const float4*)(proj + base + (size_t)1024 * 2048);
    const float4 f = *(const float4*)(proj + base + (size_t)1536 * 2048);
    projT[(size_t)(o + 0) * 512 + n] = (h16)(a.x + c.x + d.x + f.x);
    projT[(size_t)(o + 1) * 512 + n] = (h16)(a.y + c.y + d.y + f.y);
    projT[(size_t)(o + 2) * 512 + n] = (h16)(a.z + c.z + d.z + f.z);
    projT[(size_t)(o + 3) * 512 + n] = (h16)(a.w + c.w + d.w + f.w);
  }
}

// Batched causal row softmax; blockIdx.x = b*2048 + t. attn = softmax/sqrt(128).
__global__ __launch_bounds__(256) void softmax_row(const float* __restrict__ sc,
                                                   h16* __restrict__ attn)
{
  const int bt = blockIdx.x;
  const int t = bt & 2047;
  const int tid = threadIdx.x;
  const int lane = tid & 63;
  const int wid = tid >> 6;
  const int len = t + 1;
  const size_t rowoff = (size_t)bt * 2048;
  const float* row = sc + rowoff;
  const int c0 = tid * 8;
  float v[8];
  if (c0 < len) {
    const float4 a = *(const float4*)(row + c0);
    const float4 b = *(const float4*)(row + c0 + 4);
    v[0] = a.x; v[1] = a.y; v[2] = a.z; v[3] = a.w;
    v[4] = b.x; v[5] = b.y; v[6] = b.z; v[7] = b.w;
#pragma unroll
    for (int j = 0; j < 8; j++)
      if (c0 + j >= len) v[j] = -INFINITY;
  } else {
#pragma unroll
    for (int j = 0; j < 8; j++) v[j] = -INFINITY;
  }
  float m = v[0];
#pragma unroll
  for (int j = 1; j < 8; j++) m = fmaxf(m, v[j]);
#pragma unroll
  for (int off = 32; off > 0; off >>= 1) m = fmaxf(m, __shfl_xor(m, off));
  __shared__ float redm[4];
  if (lane == 0) redm[wid] = m;
  __syncthreads();
  m = fmaxf(fmaxf(redm[0], redm[1]), fmaxf(redm[2], redm[3]));
  float e[8];
  float s = 0.f;
#pragma unroll
  for (int j = 0; j < 8; j++) { e[j] = expf(v[j] - m); s += e[j]; }
#pragma unroll
  for (int off = 32; off > 0; off >>= 1) s += __shfl_xor(s, off);
  __shared__ float reds[4];
  if (lane == 0) reds[wid] = s;
  __syncthreads();
  s = reds[0] + reds[1] + reds[2] + reds[3];
  const float inv = 1.f / (s * 11.313708498984761f);   // * sqrt(128)
  const int tend = ((t >> 7) + 1) << 7;                // row's causal tile end
  if (c0 < tend) {
    f16x8 o;
#pragma unroll
    for (int j = 0; j < 8; j++) o[j] = (h16)(e[j] * inv);
    *(f16x8*)(attn + rowoff + c0) = o;
  }
}

extern "C" void kernel_launch(void* const* d_in, const int* in_sizes, int n_in,
                              void* d_out, int out_size, void* d_ws, size_t ws_size,
                              hipStream_t stream)
{
  (void)in_sizes; (void)n_in;
  const float* x    = (const float*)d_in[0];
  const float* WQ   = (const float*)d_in[1];
  const float* bQv  = (const float*)d_in[2];
  const float* WK   = (const float*)d_in[3];
  const float* bKv  = (const float*)d_in[4];
  const float* WV   = (const float*)d_in[5];
  const float* bVv  = (const float*)d_in[6];
  const float* proj = (const float*)d_in[7];
  float* out = (float*)d_out;

  char* ws = (char*)d_ws;
  size_t off = 0;
  auto alloc = [&](size_t bytes) -> void* {
    off = (off + 255) & ~(size_t)255;
    void* p = ws + off;
    off += bytes;
    return p;
  };
  // x split region (64MiB = xh+xl); 4-batch scores (64MiB fp32) aliases it after projections.
  char* xregion = (char*)alloc((size_t)2 * 16777216 * 2);
  h16* xh = (h16*)xregion;
  h16* xl = (h16*)(xregion + (size_t)16777216 * 2);
  float* scores = (float*)xregion;                       // [4][2048][2048] fp32
  h16* attn = (h16*)alloc((size_t)4 * 2048 * 2048 * 2);  // [4][2048][2048] fp16

  h16* Wqk_h = (h16*)alloc((size_t)1024 * 2048 * 2);
  h16* Wqk_l = (h16*)alloc((size_t)1024 * 2048 * 2);
  h16* Wv    = (h16*)alloc((size_t)512 * 2048 * 2);
  h16* projT = (h16*)alloc((size_t)2048 * 512 * 2);
  float* bias_qk = (float*)alloc(1024 * 4);
  float* bias_v  = (float*)alloc(512 * 4);
  h16* Qh = (h16*)alloc((size_t)8192 * 512 * 2);
  h16* Ql = (h16*)alloc((size_t)8192 * 512 * 2);
  h16* Kh = (h16*)alloc((size_t)8192 * 512 * 2);
  h16* Kl = (h16*)alloc((size_t)8192 * 512 * 2);
  h16* Vt = (h16*)alloc((size_t)4 * 512 * 2048 * 2);   // [b][d][t]
  h16* Zg = (h16*)alloc((size_t)8192 * 512 * 2);
  if (off > ws_size) {           // distinctive failure signal if ws too small
    hipMemsetAsync(d_out, 0x7F, (size_t)out_size * 4, stream);
    return;
  }

  prep_all<<<21504, 256, 0, stream>>>(x, xh, xl, WQ, bQv, WK, bKv, Wqk_h, Wqk_l,
                                      bias_qk, WV, bVv, Wv, bias_v, proj, projT);

  { // Qagg+K projection: 512t M_SINGLE (96us, MfmaUtil 51%)
    GP p{};
    p.Ah = xh; p.Al = xl; p.Bh = Wqk_h; p.Bl = Wqk_l; p.bias = bias_qk;
    p.oQh = Qh; p.oQl = Ql; p.oKh = Kh; p.oKl = Kl;
    p.K = 2048; p.lda = 2048; p.ldb = 2048; p.ldc = 0;
    gemm_bt<512, 128, 128, 1, 3, EPI_SPLIT2, false, false, M_SINGLE><<<dim3(8, 64, 1), 512, 0, stream>>>(p);
  }
  { // V projection (hi-only) -> Vt; 512t dbuf 48KB
    GP p{};
    p.Ah = xh; p.Bh = Wv; p.bias = bias_v; p.outH = Vt;
    p.K = 2048; p.lda = 2048; p.ldb = 2048; p.ldc = 0;
    gemm_bt<512, 128, 64, 0, 1, EPI_VT, false, false, M_DBUF><<<dim3(8, 64, 1), 512, 0, stream>>>(p);
  }
  // xh/xl dead from here; scores alias their storage.
  { // scores = Qagg @ K^T: 256t single-buffer, causal tile skip
    GP p{};
    p.Ah = Qh; p.Al = Ql; p.Bh = Kh; p.Bl = Kl; p.outF = scores;
    p.K = 512; p.lda = 512; p.ldb = 512; p.ldc = 2048;
    p.sA = (size_t)2048 * 512; p.sB = (size_t)2048 * 512; p.sO = (size_t)2048 * 2048;
    gemm_bt<256, 128, 128, 1, 3, EPI_F32, true, false, M_SINGLE><<<dim3(16, 16, 4), 256, 0, stream>>>(p);
  }
  softmax_row<<<8192, 256, 0, stream>>>(scores, attn);
  { // Zg = attn @ Vt^T: 512t dbuf 48KB klim
    GP p{};
    p.Ah = attn; p.Bh = Vt; p.outH = Zg;
    p.K = 2048; p.lda = 2048; p.ldb = 2048; p.ldc = 512;
    p.sA = (size_t)2048 * 2048; p.sB = (size_t)512 * 2048; p.sO = (size_t)2048 * 512;
    gemm_bt<512, 128, 64, 0, 1, EPI_H16, false, true, M_DBUF><<<dim3(8, 16, 4), 512, 0, stream>>>(p);
  }
  { // out = Zg @ projAgg: 256t dbuf 64KB
    GP p{};
    p.Ah = Zg; p.Bh = projT; p.outF = out;
    p.K = 512; p.lda = 512; p.ldb = 512; p.ldc = 2048;
    gemm_bt<256, 128, 128, 0, 1, EPI_F32, false, false, M_DBUF><<<dim3(16, 64, 1), 256, 0, stream>>>(p);
  }
}